// Round 6
// baseline (11.539 us; speedup 1.0000x reference)
//
#include <hip/hip_runtime.h>

// MTCNN PNet stage: box gen + greedy NMS (bit-parallel monotone fixed point,
// exact-match to the reference greedy scan — validated rounds 2-5, absmax 0.0)
// + refinement. 8 blocks (one per batch) x 1024 threads (16 waves).
//   wave w (0..15): builds hp-conflict masks for rows 2w,2w+1 via 9 ballots
//                   (ONE pass per wave, all passes parallel) -> LDS
//   wave 0        : bit-packed fixed point (lane y owns row y as u32 masks)
//   threads 0..255: epilogue, 4 contiguous boxes/thread, float4 in/out,
//                   reg prefetched into registers at kernel entry.
//
// Exact-integer geometry (== f64 numpy reference), verified rounds 2-5:
//   x1=(20x+10)/3, x2=(20x+120)/3 (int div); IoU>0.5 <=> 3*inter > aA+aB.
//   Conflicts confined to the 3x3 neighborhood (max IoU at |dx|=2 is 0.490);
//   cardinal neighbors always conflict; diagonals conflict unless both
//   pair-widths are 38 (mod-3 phase rule). Batches cannot suppress each
//   other (exact offset separation) -> independent per-batch NMS.

constexpr float kThresh = 0.6f;

__global__ __launch_bounds__(1024)
void pnet_kernel(const float* __restrict__ probs,   // (8,32,32)
                 const float* __restrict__ reg,     // (8,4,32,32)
                 float* __restrict__ out)           // (8192,5)
{
    const int b    = blockIdx.x;
    const int t    = threadIdx.x;      // 0..1023
    const int lane = t & 63;
    const int wave = t >> 6;           // 0..15

    __shared__ float        ssc[1024];
    __shared__ unsigned int smk[9][32];     // [dir0..7, unk=8][row]
    __shared__ unsigned int skeepRow[32];   // final kept bitmap per row

    // ---- prefetch (threads 0..255): scores FIRST, then reg; all loads
    //      drain at the first barrier, epilogue values stay in registers ----
    float4 sc4 = {0,0,0,0}, rv0 = {0,0,0,0}, rv1 = {0,0,0,0},
           rv2 = {0,0,0,0}, rv3 = {0,0,0,0};
    if (t < 256) {
        sc4 = ((const float4*)(probs + b * 1024))[t];
        const float4* r4 = (const float4*)(reg + b * 4096);
        rv0 = r4[0 * 256 + t];
        rv1 = r4[1 * 256 + t];
        rv2 = r4[2 * 256 + t];
        rv3 = r4[3 * 256 + t];
        ((float4*)ssc)[t] = sc4;
    }
    __syncthreads();

    // ---- mask build: wave w handles pass j=w (boxes 64w..64w+63 = rows
    //      2w, 2w+1); ballots are wave-local ----
    {
        const int j = wave;
        const int n = (j << 6) | lane;
        const int x = lane & 31;
        const int y = (j << 1) | (lane >> 5);
        const float sn = ssc[n];
        const int xm3 = x % 3, ym3 = y % 3;
        unsigned long long bb;

        // hp = in-bounds && valid && higher-priority (score desc, idx asc)
        //      && IoU>0.5 (mod-3 phase rule)
#define DO_DIR(DX, DY, NEGDIR, CONF, IDX)                                   \
        {                                                                   \
            const int xj = x + (DX), yj = y + (DY);                         \
            const bool inb = ((unsigned)xj < 32u) && ((unsigned)yj < 32u);  \
            const float sj = ssc[(n + (DY) * 32 + (DX)) & 1023];            \
            const bool hp = inb && (sj >= kThresh) &&                       \
                            ((sj > sn) || ((sj == sn) && (NEGDIR))) &&      \
                            (CONF);                                         \
            bb = __ballot(hp);                                              \
            if (lane < 2)                                                   \
                smk[IDX][(j << 1) | lane] =                                 \
                    lane ? (unsigned int)(bb >> 32) : (unsigned int)bb;     \
        }
        DO_DIR(-1, -1, true,  !(xm3 == 0 && ym3 == 0), 0)
        DO_DIR( 0, -1, true,  true,                    1)
        DO_DIR(+1, -1, true,  !(xm3 == 2 && ym3 == 0), 2)
        DO_DIR(-1,  0, true,  true,                    3)
        DO_DIR(+1,  0, false, true,                    4)
        DO_DIR(-1, +1, false, !(xm3 == 0 && ym3 == 2), 5)
        DO_DIR( 0, +1, false, true,                    6)
        DO_DIR(+1, +1, false, !(xm3 == 2 && ym3 == 2), 7)
#undef DO_DIR
        bb = __ballot(sn >= kThresh);   // valid boxes start UNKNOWN
        if (lane < 2)
            smk[8][(j << 1) | lane] =
                lane ? (unsigned int)(bb >> 32) : (unsigned int)bb;
    }
    __syncthreads();

    // ---- fixed point on wave 0: no barriers, no LDS in the loop ----
    if (wave == 0) {
        unsigned int m0=0,m1=0,m2=0,m3=0,m4=0,m5=0,m6=0,m7=0;
        unsigned int unk = 0, kept = 0;
        if (lane < 32) {
            m0 = smk[0][lane]; m1 = smk[1][lane];
            m2 = smk[2][lane]; m3 = smk[3][lane];
            m4 = smk[4][lane]; m5 = smk[5][lane];
            m6 = smk[6][lane]; m7 = smk[7][lane];
            unk = smk[8][lane];
        }
        const int up = (lane + 63) & 63;   // lane 0 -> 63 (zeros = border)
        const int dn = (lane + 1)  & 63;   // lane 31 -> 32 (zeros = border)

#define STEP                                                                \
        {                                                                   \
            const unsigned int unkU = __shfl(unk,  up);                     \
            const unsigned int unkD = __shfl(unk,  dn);                     \
            const unsigned int kU   = __shfl(kept, up);                     \
            const unsigned int kD   = __shfl(kept, dn);                     \
            unsigned int anyK, anyU;                                        \
            anyK  = m0 & (kU << 1);    anyU  = m0 & (unkU << 1);            \
            anyK |= m1 &  kU;          anyU |= m1 &  unkU;                  \
            anyK |= m2 & (kU >> 1);    anyU |= m2 & (unkU >> 1);            \
            anyK |= m3 & (kept << 1);  anyU |= m3 & (unk  << 1);            \
            anyK |= m4 & (kept >> 1);  anyU |= m4 & (unk  >> 1);            \
            anyK |= m5 & (kD << 1);    anyU |= m5 & (unkD << 1);            \
            anyK |= m6 &  kD;          anyU |= m6 &  unkD;                  \
            anyK |= m7 & (kD >> 1);    anyU |= m7 & (unkD >> 1);            \
            const unsigned int nk = unk & ~anyK;                            \
            kept |= nk & ~anyU;                                             \
            unk   = nk &  anyU;                                             \
        }
        for (int r = 0; r < 160; ++r) {     // converges in ~10 steps for
            STEP                            // this data; extras are no-ops
            STEP
            STEP
            STEP
            if (__ballot(unk != 0) == 0ull) break;
        }
#undef STEP
        if (lane < 32) skeepRow[lane] = kept;
    }
    __syncthreads();

    // ---- epilogue (threads 0..255): thread t owns boxes 4t..4t+3 (row y,
    //      cols x0..x0+3); arithmetic identical to rounds 2-5 ----
    if (t < 256) {
        const int y  = t >> 3;
        const int x0 = (t & 7) << 2;
        const unsigned int krow = skeepRow[y];
        const float fy1 = (float)((20 * y + 10) / 3);
        const float fy2 = (float)((20 * y + 120) / 3);
        const float h   = fy2 - fy1;

        float4 o4[5];
        float* o = (float*)o4;
        #pragma unroll
        for (int k = 0; k < 4; ++k) {
            const int x = x0 + k;
            const float score = (k == 0) ? sc4.x : (k == 1) ? sc4.y
                              : (k == 2) ? sc4.z : sc4.w;
            const float r0 = (k == 0) ? rv0.x : (k == 1) ? rv0.y
                           : (k == 2) ? rv0.z : rv0.w;
            const float r1 = (k == 0) ? rv1.x : (k == 1) ? rv1.y
                           : (k == 2) ? rv1.z : rv1.w;
            const float r2 = (k == 0) ? rv2.x : (k == 1) ? rv2.y
                           : (k == 2) ? rv2.z : rv2.w;
            const float r3 = (k == 0) ? rv3.x : (k == 1) ? rv3.y
                           : (k == 2) ? rv3.z : rv3.w;
            const float x1 = (float)((20 * x + 10) / 3);
            const float x2 = (float)((20 * x + 120) / 3);
            const float w  = x2 - x1;
            const float qq1 = x1  + r0 * w;
            const float qq2 = fy1 + r1 * h;
            const float qq3 = x2  + r2 * w;
            const float qq4 = fy2 + r3 * h;
            const float hh = qq4 - qq2, ww = qq3 - qq1;
            const float l = fmaxf(ww, hh);
            const float rx1 = qq1 + ww * 0.5f - l * 0.5f;
            const float ry1 = qq2 + hh * 0.5f - l * 0.5f;
            const float kf = (float)((krow >> x) & 1u);
            o[5 * k + 0] = rx1 * kf;
            o[5 * k + 1] = ry1 * kf;
            o[5 * k + 2] = (rx1 + l) * kf;
            o[5 * k + 3] = (ry1 + l) * kf;
            o[5 * k + 4] = score * kf;
        }
        float4* ob = (float4*)(out + (size_t)b * 5120 + t * 20);
        #pragma unroll
        for (int q = 0; q < 5; ++q) ob[q] = o4[q];
    }
}

extern "C" void kernel_launch(void* const* d_in, const int* in_sizes, int n_in,
                              void* d_out, int out_size, void* d_ws, size_t ws_size,
                              hipStream_t stream) {
    const float* probs = (const float*)d_in[0];   // 8192 f32
    const float* reg   = (const float*)d_in[1];   // 32768 f32
    float* out = (float*)d_out;                   // 40960 f32
    pnet_kernel<<<8, 1024, 0, stream>>>(probs, reg, out);
}

// Round 7
// 10.645 us; speedup vs baseline: 1.0840x; 1.0840x over previous
//
#include <hip/hip_runtime.h>

// MTCNN PNet stage: box gen + greedy NMS (bit-parallel monotone fixed point,
// exact-match to the reference greedy scan — validated rounds 2-6, absmax 0.0)
// + refinement. 8 blocks (one per batch) x 256 threads (4 waves).
//   prefetch  : scores first, then reg -> registers (wait at use)
//   mask build: wave w does ballot passes 4w..4w+3 -> LDS          [barrier]
//   fixed pt  : ALL 4 waves run it redundantly (no final barrier) —
//               lane y<32 owns row y as u32 bitmaps; 4 shfl + bit-ops/step
//   epilogue  : keep-row via intra-wave __shfl(kept, y); float4 in/out
//
// Exact-integer geometry (== f64 numpy reference), verified rounds 2-6:
//   x1=(20x+10)/3, x2=(20x+120)/3 (int div); IoU>0.5 <=> 3*inter > aA+aB.
//   Conflicts confined to the 3x3 neighborhood (max IoU at |dx|=2: 0.490);
//   cardinals always conflict; diagonals conflict unless both pair-widths
//   are 38 (mod-3 phase rule). Batches cannot suppress each other.

constexpr float kThresh = 0.6f;

__global__ __launch_bounds__(256)
void pnet_kernel(const float* __restrict__ probs,   // (8,32,32)
                 const float* __restrict__ reg,     // (8,4,32,32)
                 float* __restrict__ out)           // (8192,5)
{
    const int b    = blockIdx.x;
    const int t    = threadIdx.x;      // 0..255
    const int lane = t & 63;
    const int wave = t >> 6;           // 0..3

    __shared__ float        ssc[1024];
    __shared__ unsigned int smk[9][32];     // [dir0..7, unk=8][row]

    // ---- prefetch: scores FIRST (LDS stage waits only on them), reg after;
    //      reg values stay in registers until the epilogue ----
    const float4 sc4 = ((const float4*)(probs + b * 1024))[t];
    const float4* r4 = (const float4*)(reg + b * 4096);
    const float4 rv0 = r4[0 * 256 + t];
    const float4 rv1 = r4[1 * 256 + t];
    const float4 rv2 = r4[2 * 256 + t];
    const float4 rv3 = r4[3 * 256 + t];
    ((float4*)ssc)[t] = sc4;
    __syncthreads();

    // ---- mask build: wave w handles passes j=4w..4w+3 (boxes j*64..j*64+63
    //      = rows 2j,2j+1); ballots are wave-local ----
    #pragma unroll
    for (int jj = 0; jj < 4; ++jj) {
        const int j = (wave << 2) | jj;
        const int n = (j << 6) | lane;
        const int x = lane & 31;
        const int y = (j << 1) | (lane >> 5);
        const float sn = ssc[n];
        const int xm3 = x % 3, ym3 = y % 3;
        unsigned long long bb;

        // hp = in-bounds && valid && higher-priority (score desc, idx asc)
        //      && IoU>0.5 (mod-3 phase rule)
#define DO_DIR(DX, DY, NEGDIR, CONF, IDX)                                   \
        {                                                                   \
            const int xj = x + (DX), yj = y + (DY);                         \
            const bool inb = ((unsigned)xj < 32u) && ((unsigned)yj < 32u);  \
            const float sj = ssc[(n + (DY) * 32 + (DX)) & 1023];            \
            const bool hp = inb && (sj >= kThresh) &&                       \
                            ((sj > sn) || ((sj == sn) && (NEGDIR))) &&      \
                            (CONF);                                         \
            bb = __ballot(hp);                                              \
            if (lane < 2)                                                   \
                smk[IDX][(j << 1) | lane] =                                 \
                    lane ? (unsigned int)(bb >> 32) : (unsigned int)bb;     \
        }
        DO_DIR(-1, -1, true,  !(xm3 == 0 && ym3 == 0), 0)
        DO_DIR( 0, -1, true,  true,                    1)
        DO_DIR(+1, -1, true,  !(xm3 == 2 && ym3 == 0), 2)
        DO_DIR(-1,  0, true,  true,                    3)
        DO_DIR(+1,  0, false, true,                    4)
        DO_DIR(-1, +1, false, !(xm3 == 0 && ym3 == 2), 5)
        DO_DIR( 0, +1, false, true,                    6)
        DO_DIR(+1, +1, false, !(xm3 == 2 && ym3 == 2), 7)
#undef DO_DIR
        bb = __ballot(sn >= kThresh);   // valid boxes start UNKNOWN
        if (lane < 2)
            smk[8][(j << 1) | lane] =
                lane ? (unsigned int)(bb >> 32) : (unsigned int)bb;
    }
    __syncthreads();

    // ---- fixed point, run redundantly by ALL 4 waves (identical result;
    //      LDS reads below are broadcasts). No barriers after this. ----
    unsigned int m0=0,m1=0,m2=0,m3=0,m4=0,m5=0,m6=0,m7=0;
    unsigned int unk = 0, kept = 0;
    if (lane < 32) {
        m0 = smk[0][lane]; m1 = smk[1][lane];
        m2 = smk[2][lane]; m3 = smk[3][lane];
        m4 = smk[4][lane]; m5 = smk[5][lane];
        m6 = smk[6][lane]; m7 = smk[7][lane];
        unk = smk[8][lane];
    }
    {
        const int up = (lane + 63) & 63;   // lane 0 -> 63 (zeros = border)
        const int dn = (lane + 1)  & 63;   // lane 31 -> 32 (zeros = border)

#define STEP                                                                \
        {                                                                   \
            const unsigned int unkU = __shfl(unk,  up);                     \
            const unsigned int unkD = __shfl(unk,  dn);                     \
            const unsigned int kU   = __shfl(kept, up);                     \
            const unsigned int kD   = __shfl(kept, dn);                     \
            unsigned int anyK, anyU;                                        \
            anyK  = m0 & (kU << 1);    anyU  = m0 & (unkU << 1);            \
            anyK |= m1 &  kU;          anyU |= m1 &  unkU;                  \
            anyK |= m2 & (kU >> 1);    anyU |= m2 & (unkU >> 1);            \
            anyK |= m3 & (kept << 1);  anyU |= m3 & (unk  << 1);            \
            anyK |= m4 & (kept >> 1);  anyU |= m4 & (unk  >> 1);            \
            anyK |= m5 & (kD << 1);    anyU |= m5 & (unkD << 1);            \
            anyK |= m6 &  kD;          anyU |= m6 &  unkD;                  \
            anyK |= m7 & (kD >> 1);    anyU |= m7 & (unkD >> 1);            \
            const unsigned int nk = unk & ~anyK;                            \
            kept |= nk & ~anyU;                                             \
            unk   = nk &  anyU;                                             \
        }
        for (int r = 0; r < 200; ++r) {   // data converges in ~10-12 steps;
            STEP STEP STEP                // bound covers any worst case
            STEP STEP STEP
            if (__ballot(unk != 0) == 0ull) break;
        }
#undef STEP
    }

    // ---- epilogue: thread t owns boxes 4t..4t+3 (row y = t>>3, within
    //      this wave's 8 rows); keep-bits via intra-wave shfl; arithmetic
    //      identical to rounds 2-6 ----
    const int y  = t >> 3;                      // 8*wave .. 8*wave+7
    const int x0 = (t & 7) << 2;
    const unsigned int krow = __shfl(kept, y);  // lane y holds row y
    const float fy1 = (float)((20 * y + 10) / 3);
    const float fy2 = (float)((20 * y + 120) / 3);
    const float h   = fy2 - fy1;

    float4 o4[5];
    float* o = (float*)o4;
    #pragma unroll
    for (int k = 0; k < 4; ++k) {
        const int x = x0 + k;
        const float score = (k == 0) ? sc4.x : (k == 1) ? sc4.y
                          : (k == 2) ? sc4.z : sc4.w;
        const float r0 = (k == 0) ? rv0.x : (k == 1) ? rv0.y
                       : (k == 2) ? rv0.z : rv0.w;
        const float r1 = (k == 0) ? rv1.x : (k == 1) ? rv1.y
                       : (k == 2) ? rv1.z : rv1.w;
        const float r2 = (k == 0) ? rv2.x : (k == 1) ? rv2.y
                       : (k == 2) ? rv2.z : rv2.w;
        const float r3 = (k == 0) ? rv3.x : (k == 1) ? rv3.y
                       : (k == 2) ? rv3.z : rv3.w;
        const float x1 = (float)((20 * x + 10) / 3);
        const float x2 = (float)((20 * x + 120) / 3);
        const float w  = x2 - x1;
        const float qq1 = x1  + r0 * w;
        const float qq2 = fy1 + r1 * h;
        const float qq3 = x2  + r2 * w;
        const float qq4 = fy2 + r3 * h;
        const float hh = qq4 - qq2, ww = qq3 - qq1;
        const float l = fmaxf(ww, hh);
        const float rx1 = qq1 + ww * 0.5f - l * 0.5f;
        const float ry1 = qq2 + hh * 0.5f - l * 0.5f;
        const float kf = (float)((krow >> x) & 1u);
        o[5 * k + 0] = rx1 * kf;
        o[5 * k + 1] = ry1 * kf;
        o[5 * k + 2] = (rx1 + l) * kf;
        o[5 * k + 3] = (ry1 + l) * kf;
        o[5 * k + 4] = score * kf;
    }
    float4* ob = (float4*)(out + (size_t)b * 5120 + t * 20);
    #pragma unroll
    for (int q = 0; q < 5; ++q) ob[q] = o4[q];
}

extern "C" void kernel_launch(void* const* d_in, const int* in_sizes, int n_in,
                              void* d_out, int out_size, void* d_ws, size_t ws_size,
                              hipStream_t stream) {
    const float* probs = (const float*)d_in[0];   // 8192 f32
    const float* reg   = (const float*)d_in[1];   // 32768 f32
    float* out = (float*)d_out;                   // 40960 f32
    pnet_kernel<<<8, 256, 0, stream>>>(probs, reg, out);
}